// Round 8
// baseline (153.230 us; speedup 1.0000x reference)
//
#include <hip/hip_runtime.h>

// Problem constants (from reference: B=8, N=8192, M=2500, P=10)
#define B_   8
#define N_   8192
#define M_   2500
#define SPP_ 250
#define EPS_ 1e-20f
#define BIGF 1e30f

// ---- roles: one fused kernel ----
// p2gt: 8 z-chunks (1024 gt) x 8 b x 5 mblk (512 preds)  = 320
// gt2p: 2 z-chunks (1280 pd) x 8 b x 16 mblk (512 gts)   = 256
#define NB_P2GT 320
#define NB_GT2P 256
#define NB_FFF  79
#define NB_ALL  (NB_P2GT + NB_GT2P + NB_FFF)   // 655

// ---- ws layout (float indices) ----
#define WS_P2GT 0            // 8 z x 20000 clamped partial minima
#define WS_GT2P 160000       // 2 z x 65536 clamped partial minima
#define WS_ACC  291072       // 20 float accumulators (atomicAdd targets)
#define WS_GC   291092       // 40 + 128 + 1 uint arrival counters
#define GC_P2   0
#define GC_G2   40
#define GC_ALL  168
// acc slots
#define A_P2   0
#define A_G2   1
#define A_E    2
#define A_G    3
#define A_MC   4
#define A_ST   5
#define A_F2I  6
#define A_E2I  7
#define A_EI   8
#define A_G2I  9
#define A_GI   10
#define A_I    11
#define A_AB   12   // 12..19 per-batch sum sqrt(A2)

typedef __attribute__((ext_vector_type(8))) short short8_t;
typedef __attribute__((ext_vector_type(4))) float float4_t;

__device__ __forceinline__ unsigned pack_bf2(float lo, float hi) {
    unsigned a = __float_as_uint(lo);
    unsigned b = __float_as_uint(hi);
    a = (a + 0x7FFFu + ((a >> 16) & 1u)) >> 16;
    b = (b + 0x7FFFu + ((b >> 16) & 1u)) & 0xFFFF0000u;
    return a | b;
}
__device__ __forceinline__ short bf16s(float x) {
    unsigned a = __float_as_uint(x);
    return (short)((a + 0x7FFFu + ((a >> 16) & 1u)) >> 16);
}
__device__ __forceinline__ float wave_sum64(float v) {
    #pragma unroll
    for (int o = 32; o > 0; o >>= 1) v += __shfl_down(v, o, 64);
    return v;
}
__device__ __forceinline__ float block_sum256(float v, volatile float* red4) {
    v = wave_sum64(v);
    int wid = threadIdx.x >> 6, lane = threadIdx.x & 63;
    if (lane == 0) red4[wid] = v;
    __syncthreads();
    float r = 0.f;
    if (threadIdx.x == 0) r = red4[0] + red4[1] + red4[2] + red4[3];
    __syncthreads();
    return r;
}
__device__ __forceinline__ void min4(float4_t& c, const float4_t d) {
    c.x = fminf(c.x, d.x); c.y = fminf(c.y, d.y);
    c.z = fminf(c.z, d.z); c.w = fminf(c.w, d.w);
}
__device__ __forceinline__ void quad_min4(float4_t& c) {
    #pragma unroll
    for (int m = 1; m < 16; m <<= 1) {
        c.x = fminf(c.x, __shfl_xor(c.x, m, 64));
        c.y = fminf(c.y, __shfl_xor(c.y, m, 64));
        c.z = fminf(c.z, __shfl_xor(c.z, m, 64));
        c.w = fminf(c.w, __shfl_xor(c.w, m, 64));
    }
}

// ============================================================================
// Single fused kernel. Chamfer via bf16 MFMA 16x16x32 (K=4 used; A={x,y,z,1},
// B={-2bx,-2by,-2bz,|b|^2}, C = row-norm bias -> D = d^2 directly).
// 8 A-tiles (128 rows) per wave share each ds_read_b128 B-fragment.
// z-chunk minima merged by the LAST z-block per column-group (device-scope
// counters); fff variance terms expanded so one pass suffices; grid-last
// block computes the scalar loss. Counters/acc pre-zeroed by a 756 B memset.
// ============================================================================
__global__ void __launch_bounds__(256) fused_all(
        const float* __restrict__ gt, const float* __restrict__ pred,
        const float* __restrict__ fff, const float* __restrict__ A_gt,
        float* __restrict__ ws, float* __restrict__ out) {
    __shared__ uint4 spts[1280];                 // staged B pts, 16 B each
    __shared__ __align__(16) float saux[516];    // 512 row norms + red4
    __shared__ bool isred;
    const int bid = blockIdx.x;
    const int tid = threadIdx.x;
    const int lane = tid & 63;
    const int w    = tid >> 6;
    const int quad = lane >> 4;
    const int l15  = lane & 15;
    float* acc = ws + WS_ACC;
    unsigned* gc = (unsigned*)(ws + WS_GC);

    if (bid < NB_P2GT + NB_GT2P) {
        // ------------------- chamfer role -------------------
        const bool is_p2gt = bid < NB_P2GT;
        int b, mblk, z, ntiles, blim, alim, gidx, nz;
        const float* apts; const float* bpts; float* dst;
        if (is_p2gt) {
            z = bid / 40; int rem = bid % 40;
            b = rem / 5;  mblk = rem % 5;
            apts = pred + (size_t)b * M_ * 3;
            bpts = gt + ((size_t)b * N_ + (size_t)z * 1024) * 3;
            ntiles = 64; blim = 1024; alim = M_;
            dst  = ws + WS_P2GT + (size_t)z * 20000 + b * M_;
            gidx = GC_P2 + b * 5 + mblk; nz = 8;
        } else {
            int r = bid - NB_P2GT;
            z = r >> 7; int rem = r & 127;
            b = rem >> 4; mblk = rem & 15;
            apts = gt + (size_t)b * N_ * 3;
            bpts = pred + ((size_t)b * M_ + (size_t)z * 1280) * 3;
            ntiles = 80; blim = M_ - z * 1280; alim = N_;
            dst  = ws + WS_GT2P + (size_t)z * 65536 + b * N_;
            gidx = GC_G2 + b * 16 + mblk; nz = 2;
        }
        const int abase = mblk * 512;
        const int nstage = ntiles * 16;

        // stage B points (bf16, -2 folded, norm in w; halves duplicated)
        for (int i = tid; i < nstage; i += 256) {
            float x = 0.f, y = 0.f, zc = 0.f, n2 = BIGF;
            if (i < blim) {
                x = bpts[i * 3 + 0]; y = bpts[i * 3 + 1]; zc = bpts[i * 3 + 2];
                n2 = x * x + y * y + zc * zc;
            }
            uint4 q;
            q.x = pack_bf2(-2.f * x, -2.f * y);
            q.y = pack_bf2(-2.f * zc, n2);
            q.z = q.x; q.w = q.y;
            spts[i] = q;
        }

        // A fragments: 8 tiles of 16 rows per wave (128 rows); stash norms
        short8_t af[8];
        #pragma unroll
        for (int t = 0; t < 8; ++t) af[t] = (short8_t){0,0,0,0,0,0,0,0};
        if (lane < 16) {
            #pragma unroll
            for (int t = 0; t < 8; ++t) {
                int m = abase + w * 128 + t * 16 + l15;
                int c = m < alim ? m : alim - 1;
                float x = apts[c*3+0], y = apts[c*3+1], zc = apts[c*3+2];
                af[t][0] = bf16s(x); af[t][1] = bf16s(y); af[t][2] = bf16s(zc);
                af[t][3] = (short)0x3F80;  // 1.0 bf16
                saux[w * 128 + t * 16 + l15] = x*x + y*y + zc*zc;
            }
        }
        __syncthreads();

        const float4_t* bp = (const float4_t*)saux;
        float4_t bias[8], c[8];
        #pragma unroll
        for (int t = 0; t < 8; ++t) {
            bias[t] = bp[w * 32 + t * 4 + quad];
            c[t] = (float4_t){BIGF, BIGF, BIGF, BIGF};
        }

        const uint4* bptr = spts + l15;
        #pragma unroll 2
        for (int i = 0; i < ntiles; ++i) {
            short8_t bf = __builtin_bit_cast(short8_t, bptr[i * 16]);
            #pragma unroll
            for (int t = 0; t < 8; ++t) {
                float4_t d = __builtin_amdgcn_mfma_f32_16x16x32_bf16(
                                 af[t], bf, bias[t], 0, 0, 0);
                min4(c[t], d);
            }
        }
        #pragma unroll
        for (int t = 0; t < 8; ++t) {
            quad_min4(c[t]);
            c[t].x = fmaxf(c[t].x, 0.f); c[t].y = fmaxf(c[t].y, 0.f);
            c[t].z = fmaxf(c[t].z, 0.f); c[t].w = fmaxf(c[t].w, 0.f);
        }
        if (l15 == 0) {
            #pragma unroll
            for (int t = 0; t < 8; ++t) {
                int m0 = abase + w * 128 + t * 16 + quad * 4;
                if (m0 < alim)   // alim % 4 == 0 -> no straddle
                    *(float4_t*)(dst + m0) = c[t];
            }
        }

        // ---- group arrival: last z-block reduces min-over-z, sums, adds
        __threadfence();
        __syncthreads();
        if (tid == 0) {
            unsigned old = __hip_atomic_fetch_add(&gc[gidx], 1u,
                              __ATOMIC_ACQ_REL, __HIP_MEMORY_SCOPE_AGENT);
            isred = (old == (unsigned)(nz - 1));
        }
        __syncthreads();
        if (isred) {
            float s = 0.f;
            #pragma unroll
            for (int h = 0; h < 2; ++h) {
                int m = abase + h * 256 + tid;
                if (m < alim) {
                    const float* src = (is_p2gt ? ws + WS_P2GT + b * M_
                                                : ws + WS_GT2P + b * N_) + m;
                    int stride = is_p2gt ? 20000 : 65536;
                    float v = src[0];
                    for (int zz = 1; zz < nz; ++zz)
                        v = fminf(v, src[(size_t)zz * stride]);
                    s += v;
                }
            }
            float r = block_sum256(s, saux + 512);
            if (tid == 0) atomicAdd(&acc[is_p2gt ? A_P2 : A_G2], r);
        }
    } else {
        // ------------------- fff role (single pass) -------------------
        const int kb = bid - NB_P2GT - NB_GT2P;
        const int i  = kb * 256 + tid;
        volatile float* red4 = saux + 512;
        float* sA = saux;   // [0..7]
        if (tid < B_) sA[tid] = 0.f;
        __syncthreads();

        float vE=0.f,vG=0.f,vMC=0.f,vST=0.f,vF2=0.f,vE2=0.f,vEI=0.f,
              vG2=0.f,vGI=0.f,vI=0.f;
        if (i < B_ * M_) {
            const int b = i / M_;
            const int m = i - b * M_;
            const float* f = fff + (size_t)i * 3;
            float E = f[0], F = f[1], G = f[2];
            float A2  = fmaxf(E * G - F * F, 0.f);
            float inv = 1.f / (A2 + EPS_);
            vE = E; vG = G;
            vST = (E - G) * (E - G) * inv;
            vF2 = F * F * inv;
            vE2 = E * E * inv; vEI = E * inv;
            vG2 = G * G * inv; vGI = G * inv;
            vI  = inv;
            atomicAdd(&sA[b], sqrtf(A2));
            if ((b & 1) == 0) {
                const float* f2 = fff + ((size_t)(b + 1) * M_ + m) * 3;
                float dE = E - f2[0], dF = F - f2[1], dG = G - f2[2];
                vMC = dE * dE + 2.f * dF * dF + dG * dG;
            }
        }
        float r;
        r = block_sum256(vE,  red4); if (tid==0) atomicAdd(&acc[A_E],   r);
        r = block_sum256(vG,  red4); if (tid==0) atomicAdd(&acc[A_G],   r);
        r = block_sum256(vMC, red4); if (tid==0) atomicAdd(&acc[A_MC],  r);
        r = block_sum256(vST, red4); if (tid==0) atomicAdd(&acc[A_ST],  r);
        r = block_sum256(vF2, red4); if (tid==0) atomicAdd(&acc[A_F2I], r);
        r = block_sum256(vE2, red4); if (tid==0) atomicAdd(&acc[A_E2I], r);
        r = block_sum256(vEI, red4); if (tid==0) atomicAdd(&acc[A_EI],  r);
        r = block_sum256(vG2, red4); if (tid==0) atomicAdd(&acc[A_G2I], r);
        r = block_sum256(vGI, red4); if (tid==0) atomicAdd(&acc[A_GI],  r);
        r = block_sum256(vI,  red4); if (tid==0) atomicAdd(&acc[A_I],   r);
        __syncthreads();
        if (tid < B_ && sA[tid] != 0.f) atomicAdd(&acc[A_AB + tid], sA[tid]);
    }

    // ---- grid arrival: last block computes the scalar loss ----
    __syncthreads();
    if (tid == 0) {
        __threadfence();
        unsigned old = __hip_atomic_fetch_add(&gc[GC_ALL], 1u,
                          __ATOMIC_ACQ_REL, __HIP_MEMORY_SCOPE_AGENT);
        if (old == (unsigned)(NB_ALL - 1)) {
            float a[20];
            #pragma unroll
            for (int k = 0; k < 20; ++k)
                a[k] = __hip_atomic_load(&acc[k], __ATOMIC_RELAXED,
                                         __HIP_MEMORY_SCOPE_AGENT);
            const float inv20k = 1.f / 20000.f;
            float mE = a[A_E] * inv20k, mG = a[A_G] * inv20k;
            float L_E = (a[A_E2I] - 2.f*mE*a[A_EI] + mE*mE*a[A_I]) * inv20k;
            float L_G = (a[A_G2I] - 2.f*mG*a[A_GI] + mG*mG*a[A_I]) * inv20k;
            float L_sc = L_E + L_G + (a[A_ST] + a[A_F2I]) * inv20k;
            float L_mc = a[A_MC] * (1.f / 10000.f);
            float L_chd = a[A_P2] * inv20k + a[A_G2] * (1.f / 65536.f);
            float L_olap = 0.f;
            #pragma unroll
            for (int b = 0; b < B_; ++b) {
                float At = a[A_AB + b] * (1.f / (float)SPP_);
                float d  = fmaxf(0.f, At - A_gt[b]);
                L_olap += d * d;
            }
            L_olap *= (1.f / (float)B_);
            out[0] = L_chd + L_mc + L_sc + L_olap;
        }
    }
}

extern "C" void kernel_launch(void* const* d_in, const int* in_sizes, int n_in,
                              void* d_out, int out_size, void* d_ws, size_t ws_size,
                              hipStream_t stream) {
    const float* pc_gt   = (const float*)d_in[0];   // (8, 8192, 3)
    const float* pc_pred = (const float*)d_in[1];   // (8, 2500, 3)
    const float* fff     = (const float*)d_in[2];   // (8, 2500, 3)
    const float* A_gt    = (const float*)d_in[3];   // (8,)
    float* ws  = (float*)d_ws;                      // ~1.2 MB used
    float* out = (float*)d_out;

    // zero 20 float accumulators + 169 uint counters (756 B)
    hipMemsetAsync(ws + WS_ACC, 0, (20 + 169) * sizeof(float), stream);
    fused_all<<<NB_ALL, 256, 0, stream>>>(pc_gt, pc_pred, fff, A_gt, ws, out);
}

// Round 9
// 96.792 us; speedup vs baseline: 1.5831x; 1.5831x over previous
//
#include <hip/hip_runtime.h>

// Problem constants (from reference: B=8, N=8192, M=2500, P=10)
#define B_   8
#define N_   8192
#define M_   2500
#define SPP_ 250
#define EPS_ 1e-20f
#define BIGF 1e30f

// ---- kernel-1 roles ----
// p2gt: 8 z-chunks (1024 gt) x 8 b x 5 mblk (512 preds)  = 320
// gt2p: 2 z-chunks (1280 pd) x 8 b x 16 mblk (512 gts)   = 256
#define NB_P2GT 320
#define NB_GT2P 256
#define NB_FFF  79
#define NB_K1   (NB_P2GT + NB_GT2P + NB_FFF)   // 655

// ---- kernel-2 roles ----
#define NB_RG2P 256
#define NB_RP2  79
#define NB_K2   (NB_RG2P + NB_RP2)             // 335

// ---- ws layout (float indices) ----
#define WS_P2GT 0            // 8 z x 20000 clamped partial minima
#define WS_GT2P 160000       // 2 z x 65536 clamped partial minima
#define WS_ACC  291072       // 20 float accumulators (atomicAdd targets, k1)
#define WS_RED  291092       // k2 partials: 256 g2p + 79 p2
#define WS_CNT  291427       // k2 arrival counter (uint)
// acc slots
#define A_E    0
#define A_G    1
#define A_MC   2
#define A_ST   3
#define A_F2I  4
#define A_E2I  5
#define A_EI   6
#define A_G2I  7
#define A_GI   8
#define A_I    9
#define A_AB   10   // 10..17 per-batch sum sqrt(A2)
#define RO_G2P 0
#define RO_P2  256

typedef __attribute__((ext_vector_type(8))) short short8_t;
typedef __attribute__((ext_vector_type(4))) float float4_t;

__device__ __forceinline__ unsigned pack_bf2(float lo, float hi) {
    unsigned a = __float_as_uint(lo);
    unsigned b = __float_as_uint(hi);
    a = (a + 0x7FFFu + ((a >> 16) & 1u)) >> 16;
    b = (b + 0x7FFFu + ((b >> 16) & 1u)) & 0xFFFF0000u;
    return a | b;
}
__device__ __forceinline__ short bf16s(float x) {
    unsigned a = __float_as_uint(x);
    return (short)((a + 0x7FFFu + ((a >> 16) & 1u)) >> 16);
}
__device__ __forceinline__ float wave_sum64(float v) {
    #pragma unroll
    for (int o = 32; o > 0; o >>= 1) v += __shfl_down(v, o, 64);
    return v;
}
__device__ __forceinline__ float block_sum256(float v, volatile float* red4) {
    v = wave_sum64(v);
    int wid = threadIdx.x >> 6, lane = threadIdx.x & 63;
    if (lane == 0) red4[wid] = v;
    __syncthreads();
    float r = 0.f;
    if (threadIdx.x == 0) r = red4[0] + red4[1] + red4[2] + red4[3];
    __syncthreads();
    return r;
}
__device__ __forceinline__ void min4(float4_t& c, const float4_t d) {
    c.x = fminf(c.x, d.x); c.y = fminf(c.y, d.y);
    c.z = fminf(c.z, d.z); c.w = fminf(c.w, d.w);
}
__device__ __forceinline__ void quad_min4(float4_t& c) {
    #pragma unroll
    for (int m = 1; m < 16; m <<= 1) {
        c.x = fminf(c.x, __shfl_xor(c.x, m, 64));
        c.y = fminf(c.y, __shfl_xor(c.y, m, 64));
        c.z = fminf(c.z, __shfl_xor(c.z, m, 64));
        c.w = fminf(c.w, __shfl_xor(c.w, m, 64));
    }
}

// ============================================================================
// Kernel 1: MFMA chamfer (both directions) + single-pass fff.
// 8 A-tiles (128 rows) per wave share each ds_read_b128 B-fragment.
// __launch_bounds__(256, 2): allow up to 256 VGPR/wave so the ~130 live regs
// (8x af/bias/c tuples) DON'T spill to scratch (r8's 72-VGPR spill = 100 us).
// No device fences / cross-block protocol here — pure compute + stores.
// ============================================================================
__global__ void __launch_bounds__(256, 2) k1_main(
        const float* __restrict__ gt, const float* __restrict__ pred,
        const float* __restrict__ fff, float* __restrict__ ws) {
    __shared__ uint4 spts[1280];                 // staged B pts, 16 B each
    __shared__ __align__(16) float saux[516];    // 512 row norms + red4
    const int bid = blockIdx.x;
    const int tid = threadIdx.x;
    const int lane = tid & 63;
    const int w    = tid >> 6;
    const int quad = lane >> 4;
    const int l15  = lane & 15;
    float* acc = ws + WS_ACC;

    if (bid == 0 && tid == 0) ((unsigned*)(ws + WS_CNT))[0] = 0u;

    if (bid < NB_P2GT + NB_GT2P) {
        // ------------------- chamfer role -------------------
        const bool is_p2gt = bid < NB_P2GT;
        int b, mblk, z, ntiles, blim, alim;
        const float* apts; const float* bpts; float* dst;
        if (is_p2gt) {
            z = bid / 40; int rem = bid % 40;
            b = rem / 5;  mblk = rem % 5;
            apts = pred + (size_t)b * M_ * 3;
            bpts = gt + ((size_t)b * N_ + (size_t)z * 1024) * 3;
            ntiles = 64; blim = 1024; alim = M_;
            dst = ws + WS_P2GT + (size_t)z * 20000 + b * M_;
        } else {
            int r = bid - NB_P2GT;
            z = r >> 7; int rem = r & 127;
            b = rem >> 4; mblk = rem & 15;
            apts = gt + (size_t)b * N_ * 3;
            bpts = pred + ((size_t)b * M_ + (size_t)z * 1280) * 3;
            ntiles = 80; blim = M_ - z * 1280; alim = N_;
            dst = ws + WS_GT2P + (size_t)z * 65536 + b * N_;
        }
        const int abase = mblk * 512;
        const int nstage = ntiles * 16;

        // stage B points (bf16, -2 folded, norm in w; halves duplicated)
        for (int i = tid; i < nstage; i += 256) {
            float x = 0.f, y = 0.f, zc = 0.f, n2 = BIGF;
            if (i < blim) {
                x = bpts[i * 3 + 0]; y = bpts[i * 3 + 1]; zc = bpts[i * 3 + 2];
                n2 = x * x + y * y + zc * zc;
            }
            uint4 q;
            q.x = pack_bf2(-2.f * x, -2.f * y);
            q.y = pack_bf2(-2.f * zc, n2);
            q.z = q.x; q.w = q.y;
            spts[i] = q;
        }

        // A fragments: 8 tiles of 16 rows per wave (128 rows); stash norms
        short8_t af[8];
        #pragma unroll
        for (int t = 0; t < 8; ++t) af[t] = (short8_t){0,0,0,0,0,0,0,0};
        if (lane < 16) {
            #pragma unroll
            for (int t = 0; t < 8; ++t) {
                int m = abase + w * 128 + t * 16 + l15;
                int c = m < alim ? m : alim - 1;
                float x = apts[c*3+0], y = apts[c*3+1], zc = apts[c*3+2];
                af[t][0] = bf16s(x); af[t][1] = bf16s(y); af[t][2] = bf16s(zc);
                af[t][3] = (short)0x3F80;  // 1.0 bf16
                saux[w * 128 + t * 16 + l15] = x*x + y*y + zc*zc;
            }
        }
        __syncthreads();

        const float4_t* bp = (const float4_t*)saux;
        float4_t bias[8], c[8];
        #pragma unroll
        for (int t = 0; t < 8; ++t) {
            bias[t] = bp[w * 32 + t * 4 + quad];
            c[t] = (float4_t){BIGF, BIGF, BIGF, BIGF};
        }

        const uint4* bptr = spts + l15;   // quads duplicate address = broadcast
        #pragma unroll 2
        for (int i = 0; i < ntiles; ++i) {
            short8_t bf = __builtin_bit_cast(short8_t, bptr[i * 16]);
            #pragma unroll
            for (int t = 0; t < 8; ++t) {
                float4_t d = __builtin_amdgcn_mfma_f32_16x16x32_bf16(
                                 af[t], bf, bias[t], 0, 0, 0);
                min4(c[t], d);
            }
        }
        #pragma unroll
        for (int t = 0; t < 8; ++t) {
            quad_min4(c[t]);
            c[t].x = fmaxf(c[t].x, 0.f); c[t].y = fmaxf(c[t].y, 0.f);
            c[t].z = fmaxf(c[t].z, 0.f); c[t].w = fmaxf(c[t].w, 0.f);
        }
        if (l15 == 0) {
            #pragma unroll
            for (int t = 0; t < 8; ++t) {
                int m0 = abase + w * 128 + t * 16 + quad * 4;
                if (m0 < alim)   // alim % 4 == 0 -> no straddle
                    *(float4_t*)(dst + m0) = c[t];
            }
        }
    } else {
        // ------------- fff role (single pass, expanded variance) -------------
        const int kb = bid - NB_P2GT - NB_GT2P;
        const int i  = kb * 256 + tid;
        volatile float* red4 = saux + 512;
        float* sA = saux;   // [0..7]
        if (tid < B_) sA[tid] = 0.f;
        __syncthreads();

        float vE=0.f,vG=0.f,vMC=0.f,vST=0.f,vF2=0.f,vE2=0.f,vEI=0.f,
              vG2=0.f,vGI=0.f,vI=0.f;
        if (i < B_ * M_) {
            const int b = i / M_;
            const int m = i - b * M_;
            const float* f = fff + (size_t)i * 3;
            float E = f[0], F = f[1], G = f[2];
            float A2  = fmaxf(E * G - F * F, 0.f);
            float inv = 1.f / (A2 + EPS_);
            vE = E; vG = G;
            vST = (E - G) * (E - G) * inv;
            vF2 = F * F * inv;
            vE2 = E * E * inv; vEI = E * inv;
            vG2 = G * G * inv; vGI = G * inv;
            vI  = inv;
            atomicAdd(&sA[b], sqrtf(A2));
            if ((b & 1) == 0) {
                const float* f2 = fff + ((size_t)(b + 1) * M_ + m) * 3;
                float dE = E - f2[0], dF = F - f2[1], dG = G - f2[2];
                vMC = dE * dE + 2.f * dF * dF + dG * dG;
            }
        }
        float r;
        r = block_sum256(vE,  red4); if (tid==0) atomicAdd(&acc[A_E],   r);
        r = block_sum256(vG,  red4); if (tid==0) atomicAdd(&acc[A_G],   r);
        r = block_sum256(vMC, red4); if (tid==0) atomicAdd(&acc[A_MC],  r);
        r = block_sum256(vST, red4); if (tid==0) atomicAdd(&acc[A_ST],  r);
        r = block_sum256(vF2, red4); if (tid==0) atomicAdd(&acc[A_F2I], r);
        r = block_sum256(vE2, red4); if (tid==0) atomicAdd(&acc[A_E2I], r);
        r = block_sum256(vEI, red4); if (tid==0) atomicAdd(&acc[A_EI],  r);
        r = block_sum256(vG2, red4); if (tid==0) atomicAdd(&acc[A_G2I], r);
        r = block_sum256(vGI, red4); if (tid==0) atomicAdd(&acc[A_GI],  r);
        r = block_sum256(vI,  red4); if (tid==0) atomicAdd(&acc[A_I],   r);
        __syncthreads();
        if (tid < B_ && sA[tid] != 0.f) atomicAdd(&acc[A_AB + tid], sA[tid]);
    }
}

// ============================================================================
// Kernel 2: min-over-z both directions + last-block finalize.
// ============================================================================
__global__ void __launch_bounds__(256) k2_reduce(
        const float* __restrict__ fff, const float* __restrict__ A_gt,
        float* __restrict__ ws, float* __restrict__ out) {
    __shared__ float red4[4];
    const int bid = blockIdx.x;
    const int tid = threadIdx.x;
    float* redp = ws + WS_RED;
    float* acc  = ws + WS_ACC;

    if (bid < NB_RG2P) {
        const int o = bid * 256 + tid;               // [0,65536)
        const float* src = ws + WS_GT2P + o;
        float m = fminf(src[0], src[65536]);         // already clamped
        float r = block_sum256(m, red4);
        if (tid == 0) redp[RO_G2P + bid] = r;
    } else {
        const int kb = bid - NB_RG2P;
        const int o = kb * 256 + tid;                // [0,20224)
        float s = 0.f;
        if (o < 20000) {
            const float* src = ws + WS_P2GT + o;
            float m = src[0];
            #pragma unroll
            for (int zz = 1; zz < 8; ++zz) m = fminf(m, src[zz * 20000]);
            s = m;
        }
        float r = block_sum256(s, red4);
        if (tid == 0) redp[RO_P2 + kb] = r;
    }

    // ---- arrival counter; last block finalizes ----
    __syncthreads();
    if (tid == 0) __threadfence();
    __syncthreads();
    __shared__ unsigned old_s;
    if (tid == 0)
        old_s = __hip_atomic_fetch_add((unsigned*)(ws + WS_CNT), 1u,
                                       __ATOMIC_ACQ_REL, __HIP_MEMORY_SCOPE_AGENT);
    __syncthreads();
    if (old_s == (unsigned)(NB_K2 - 1)) {
        float v;
        v = redp[RO_G2P + tid];
        float sGT2P = block_sum256(v, red4);
        v = (tid < 79) ? redp[RO_P2 + tid] : 0.f;
        float sP2GT = block_sum256(v, red4);
        if (tid == 0) {
            float a[18];
            #pragma unroll
            for (int k = 0; k < 18; ++k)
                a[k] = __hip_atomic_load(&acc[k], __ATOMIC_RELAXED,
                                         __HIP_MEMORY_SCOPE_AGENT);
            const float inv20k = 1.f / 20000.f;
            float mE = a[A_E] * inv20k, mG = a[A_G] * inv20k;
            float L_E = (a[A_E2I] - 2.f*mE*a[A_EI] + mE*mE*a[A_I]) * inv20k;
            float L_G = (a[A_G2I] - 2.f*mG*a[A_GI] + mG*mG*a[A_I]) * inv20k;
            float L_sc = L_E + L_G + (a[A_ST] + a[A_F2I]) * inv20k;
            float L_mc = a[A_MC] * (1.f / 10000.f);
            float L_chd = sP2GT * inv20k + sGT2P * (1.f / 65536.f);
            float L_olap = 0.f;
            #pragma unroll
            for (int b = 0; b < B_; ++b) {
                float At = a[A_AB + b] * (1.f / (float)SPP_);
                float d  = fmaxf(0.f, At - A_gt[b]);
                L_olap += d * d;
            }
            L_olap *= (1.f / (float)B_);
            out[0] = L_chd + L_mc + L_sc + L_olap;
        }
    }
}

extern "C" void kernel_launch(void* const* d_in, const int* in_sizes, int n_in,
                              void* d_out, int out_size, void* d_ws, size_t ws_size,
                              hipStream_t stream) {
    const float* pc_gt   = (const float*)d_in[0];   // (8, 8192, 3)
    const float* pc_pred = (const float*)d_in[1];   // (8, 2500, 3)
    const float* fff     = (const float*)d_in[2];   // (8, 2500, 3)
    const float* A_gt    = (const float*)d_in[3];   // (8,)
    float* ws  = (float*)d_ws;                      // ~1.2 MB used
    float* out = (float*)d_out;

    // zero 20 float accumulators (80 B); k2 counter zeroed by k1 block 0
    hipMemsetAsync(ws + WS_ACC, 0, 20 * sizeof(float), stream);
    k1_main  <<<NB_K1, 256, 0, stream>>>(pc_gt, pc_pred, fff, ws);
    k2_reduce<<<NB_K2, 256, 0, stream>>>(fff, A_gt, ws, out);
}